// Round 11
// baseline (894.630 us; speedup 1.0000x reference)
//
#include <hip/hip_runtime.h>
#include <math.h>

#define NN 10000
#define NE 160000
#define SDIM 256
#define VDIM 32
#define L2DIM 16
#define TDIM 128
#define FEAT 528      // S + 3V + 3V + 5*L2
#define WOUT 400      // S + 4V + L2
#define ADA 592       // 2S+2V+L2
#define DEG_INV 0.25f

#define ETM 16        // edges per block
#define WLP 400       // w LDS stride (bf16 elems)
#define AP1 72        // misc A stride (bf16) -- aliased into wl
#define AP2 392       // nodeproj A stride (bf16)
#define AP3 264       // proj kernel A stride (bf16)
#define HSP 528       // staged h row stride (bf16 elems)

typedef short bf16x8 __attribute__((ext_vector_type(8)));
typedef float f32x4 __attribute__((ext_vector_type(4)));

__device__ __forceinline__ unsigned short f2bf(float f) {
    unsigned int u = __float_as_uint(f);
    u += 0x7fffu + ((u >> 16) & 1u);      // round-to-nearest-even
    return (unsigned short)(u >> 16);
}
__device__ __forceinline__ float bf2f(unsigned short b) {
    return __uint_as_float(((unsigned int)b) << 16);
}

// ================================================================ sort by dst
__global__ __launch_bounds__(256) void hist_kernel(const int* __restrict__ eidx,
                                                   int* __restrict__ cnt) {
    int e = blockIdx.x * 256 + threadIdx.x;
    if (e < NE) atomicAdd(&cnt[eidx[NE + e]], 1);
}

__global__ __launch_bounds__(1024) void scan_kernel(const int* __restrict__ cnt,
                                                    int* __restrict__ cursor) {
    __shared__ int sc[1024];
    int tid = threadIdx.x;
    int base = tid * 10;
    int loc[10];
    int s = 0;
    if (base < NN) {
        #pragma unroll
        for (int j = 0; j < 10; ++j) { loc[j] = cnt[base + j]; s += loc[j]; }
    }
    sc[tid] = s;
    __syncthreads();
    for (int off = 1; off < 1024; off <<= 1) {
        int v = sc[tid];
        int add = (tid >= off) ? sc[tid - off] : 0;
        __syncthreads();
        sc[tid] = v + add;
        __syncthreads();
    }
    int run = sc[tid] - s;   // exclusive prefix
    if (base < NN) {
        #pragma unroll
        for (int j = 0; j < 10; ++j) { cursor[base + j] = run; run += loc[j]; }
    }
}

__global__ __launch_bounds__(256) void scatter_kernel(const int* __restrict__ eidx,
                                                      int* __restrict__ cursor,
                                                      int* __restrict__ perm) {
    int e = blockIdx.x * 256 + threadIdx.x;
    if (e < NE) {
        int d = eidx[NE + e];
        int p = atomicAdd(&cursor[d], 1);
        perm[p] = e;
    }
}

// ================================================================ fused weight prep
// Wt1[400][64], Bn[800][384], Ba[592][128], Bsv[32][256], Ps[256][256]
#define O1 25600
#define O2 332800
#define O3 408576
#define O4 416768
#define O5 482304
__global__ __launch_bounds__(256) void prep_kernel(
    const float* __restrict__ W, const float* __restrict__ adaW,
    const float* __restrict__ svW, const float* __restrict__ projs,
    unsigned short* __restrict__ Wt1, unsigned short* __restrict__ Bn,
    unsigned short* __restrict__ Ba, unsigned short* __restrict__ Bsv,
    unsigned short* __restrict__ Ps)
{
    int idx = blockIdx.x * 256 + threadIdx.x;
    if (idx < O1) {
        int c = idx >> 6, k = idx & 63;
        float v = (k < 60) ? W[(size_t)k * WOUT + c] : 0.f;
        Wt1[idx] = f2bf(v);
    } else if (idx < O2) {
        int i = idx - O1;
        int c = i / 384, k = i - c * 384;
        float v;
        if (c < WOUT) v = (k < 256) ? W[(size_t)(60 + k) * WOUT + c] : 0.f;
        else {
            int c2 = c - WOUT;
            v = (k < 256) ? W[(size_t)(316 + k) * WOUT + c2]
                          : W[(size_t)(572 + (k - 256)) * WOUT + c2];
        }
        Bn[i] = f2bf(v);
    } else if (idx < O3) {
        int i = idx - O2;
        int c = i >> 7, k = i & 127;
        Ba[i] = f2bf(adaW[(size_t)k * ADA + c]);
    } else if (idx < O4) {
        int i = idx - O3;
        int c = i >> 8, k = i & 255;
        Bsv[i] = f2bf(svW[(size_t)k * VDIM + c]);
    } else if (idx < O5) {
        int i = idx - O4;
        int c = i >> 8, k = i & 255;
        Ps[i] = f2bf(projs[(size_t)k * SDIM + c]);
    }
}

// ================================================================ hb = bf16(h) (input layer only)
struct us4 { unsigned short x, y, z, w; };
__global__ __launch_bounds__(256) void hb_kernel(const float* __restrict__ h,
                                                 unsigned short* __restrict__ hb) {
    int i = blockIdx.x * 256 + threadIdx.x;
    if (i >= NN * FEAT / 4) return;
    float4 v = ((const float4*)h)[i];
    us4 o;
    o.x = f2bf(v.x); o.y = f2bf(v.y); o.z = f2bf(v.z); o.w = f2bf(v.w);
    ((us4*)hb)[i] = o;
}

// ================================================================ nodeproj: srcdst (bf16) + ada (f32) + sv (f32)
__global__ __launch_bounds__(256) void nodeproj_kernel(
    const unsigned short* __restrict__ hb, const float* __restrict__ t_emb,
    const unsigned short* __restrict__ Bn, const unsigned short* __restrict__ Ba,
    const unsigned short* __restrict__ Bsv,
    const float* __restrict__ edge_b, const float* __restrict__ adab,
    unsigned short* __restrict__ srcdst, float* __restrict__ ada_out,
    float* __restrict__ sv)
{
    __shared__ unsigned short As2[32 * AP2];
    const int tid = threadIdx.x;
    const int n0 = blockIdx.x * 32;

    for (int e = 0; e < 32; ++e) {
        int n = n0 + e;
        As2[e * AP2 + tid] = (n < NN) ? hb[(size_t)n * FEAT + tid] : 0;
        if (tid < 128) {
            float v1 = (n < NN) ? t_emb[(size_t)n * TDIM + tid] : 0.f;
            As2[e * AP2 + 256 + tid] = f2bf(v1);
        }
    }
    __syncthreads();

    const int wid = tid >> 6, lane = tid & 63;
    const int lr = lane & 15, lkb = (lane >> 4) << 3;
    const int rbase = (lane >> 4) << 2;

    // ---- main: 50 tiles, K=384
    {
        const int nt0 = wid * 13;
        f32x4 acc[2][13];
        #pragma unroll
        for (int m = 0; m < 2; ++m)
            #pragma unroll
            for (int t = 0; t < 13; ++t) acc[m][t] = (f32x4){0.f, 0.f, 0.f, 0.f};

        for (int ks = 0; ks < 12; ++ks) {
            int kb = ks * 32 + lkb;
            bf16x8 a0 = *(const bf16x8*)&As2[lr * AP2 + kb];
            bf16x8 a1 = *(const bf16x8*)&As2[(16 + lr) * AP2 + kb];
            #pragma unroll
            for (int t = 0; t < 13; ++t) {
                int tile = nt0 + t;
                if (tile < 50) {
                    bf16x8 b = *(const bf16x8*)&Bn[(size_t)(tile * 16 + lr) * 384 + kb];
                    acc[0][t] = __builtin_amdgcn_mfma_f32_16x16x32_bf16(a0, b, acc[0][t], 0, 0, 0);
                    acc[1][t] = __builtin_amdgcn_mfma_f32_16x16x32_bf16(a1, b, acc[1][t], 0, 0, 0);
                }
            }
        }
        #pragma unroll
        for (int t = 0; t < 13; ++t) {
            int tile = nt0 + t;
            if (tile < 50) {
                int col = tile * 16 + lr;
                float badd = (col >= WOUT) ? edge_b[col - WOUT] : 0.f;
                #pragma unroll
                for (int m = 0; m < 2; ++m) {
                    #pragma unroll
                    for (int r = 0; r < 4; ++r) {
                        int n = n0 + m * 16 + rbase + r;
                        if (n < NN) srcdst[(size_t)n * 800 + col] = f2bf(acc[m][t][r] + badd);
                    }
                }
            }
        }
    }

    // ---- ada: 37 tiles, K=128
    {
        const int nt0a = wid * 9;
        f32x4 acc2[2][10];
        #pragma unroll
        for (int m = 0; m < 2; ++m)
            #pragma unroll
            for (int t = 0; t < 10; ++t) acc2[m][t] = (f32x4){0.f, 0.f, 0.f, 0.f};

        for (int ks = 0; ks < 4; ++ks) {
            int kin = ks * 32 + lkb;
            bf16x8 a0 = *(const bf16x8*)&As2[lr * AP2 + 256 + kin];
            bf16x8 a1 = *(const bf16x8*)&As2[(16 + lr) * AP2 + 256 + kin];
            #pragma unroll
            for (int t = 0; t < 10; ++t) {
                int tile = nt0a + t;
                if (tile < 37) {
                    bf16x8 b = *(const bf16x8*)&Ba[(size_t)(tile * 16 + lr) * 128 + kin];
                    acc2[0][t] = __builtin_amdgcn_mfma_f32_16x16x32_bf16(a0, b, acc2[0][t], 0, 0, 0);
                    acc2[1][t] = __builtin_amdgcn_mfma_f32_16x16x32_bf16(a1, b, acc2[1][t], 0, 0, 0);
                }
            }
        }
        #pragma unroll
        for (int t = 0; t < 10; ++t) {
            int tile = nt0a + t;
            if (tile < 37) {
                int col = tile * 16 + lr;
                float badd = adab[col];
                #pragma unroll
                for (int m = 0; m < 2; ++m) {
                    #pragma unroll
                    for (int r = 0; r < 4; ++r) {
                        int n = n0 + m * 16 + rbase + r;
                        if (n < NN) ada_out[(size_t)n * ADA + col] = acc2[m][t][r] + badd;
                    }
                }
            }
        }
    }

    // ---- sv: 2 tiles (waves 0,1), K=256
    if (wid < 2) {
        f32x4 accs[2];
        accs[0] = (f32x4){0.f, 0.f, 0.f, 0.f};
        accs[1] = (f32x4){0.f, 0.f, 0.f, 0.f};
        for (int ks = 0; ks < 8; ++ks) {
            int kb = ks * 32 + lkb;
            bf16x8 a0 = *(const bf16x8*)&As2[lr * AP2 + kb];
            bf16x8 a1 = *(const bf16x8*)&As2[(16 + lr) * AP2 + kb];
            bf16x8 b = *(const bf16x8*)&Bsv[(size_t)(wid * 16 + lr) * 256 + kb];
            accs[0] = __builtin_amdgcn_mfma_f32_16x16x32_bf16(a0, b, accs[0], 0, 0, 0);
            accs[1] = __builtin_amdgcn_mfma_f32_16x16x32_bf16(a1, b, accs[1], 0, 0, 0);
        }
        int col = wid * 16 + lr;
        #pragma unroll
        for (int m = 0; m < 2; ++m) {
            #pragma unroll
            for (int r = 0; r < 4; ++r) {
                int n = n0 + m * 16 + rbase + r;
                if (n < NN) sv[(size_t)n * VDIM + col] = accs[m][r];
            }
        }
    }
}

// ================================================================ edge kernel (LDS-diet: 5 blocks/CU)
__global__ __launch_bounds__(256) void edge_kernel(
    const unsigned short* __restrict__ hb, const float* __restrict__ coords,
    const float* __restrict__ erd, const float* __restrict__ sv,
    const unsigned short* __restrict__ Wt1, const unsigned short* __restrict__ srcdst,
    const int* __restrict__ perm, const int* __restrict__ eidx,
    const int* __restrict__ etype, const int* __restrict__ ebt,
    const int* __restrict__ ebc, const int* __restrict__ ebr,
    const int* __restrict__ ebs,
    const float* __restrict__ etype_emb, const float* __restrict__ btype_emb,
    const float* __restrict__ bconj_emb, const float* __restrict__ bring_emb,
    const float* __restrict__ bstereo_emb,
    const float* __restrict__ refW, const float* __restrict__ refb,
    float* __restrict__ agg)
{
    __shared__ unsigned short wl[ETM * WLP];     // 12.8 KB (bf16 w; first 1152 aliased as As)
    __shared__ unsigned short hsl[ETM * HSP];    // 16.9 KB staged src rows
    __shared__ unsigned short svl[ETM * VDIM];   // 1 KB staged sv rows (bf16)
    __shared__ int srcl[ETM], dstl[ETM];
    __shared__ int itype[ETM], ibt[ETM], ibc[ETM], ibr[ETM], ibs[ETM];
    __shared__ float distl[ETM], erdl[ETM], y1l[ETM][3];

    unsigned short* As = wl;   // alias: As dead before wl is written (barrier between)

    const int tid = threadIdx.x;
    const int bid = (blockIdx.x & 7) * 1250 + (blockIdx.x >> 3);   // XCD swizzle
    const int e0 = bid * ETM;

    if (tid < ETM) {
        int ge = perm[e0 + tid];
        int s = eidx[ge], d = eidx[NE + ge];
        srcl[tid] = s; dstl[tid] = d;
        itype[tid] = etype[ge]; ibt[tid] = ebt[ge]; ibc[tid] = ebc[ge];
        ibr[tid] = ebr[ge]; ibs[tid] = ebs[ge];
        float dx = coords[d*3+0] - coords[s*3+0];
        float dy = coords[d*3+1] - coords[s*3+1];
        float dz = coords[d*3+2] - coords[s*3+2];
        float dist = sqrtf(dx*dx + dy*dy + dz*dz);
        distl[tid] = dist;
        float inv = 1.f / (dist + 1e-8f);
        y1l[tid][0] = dx * inv; y1l[tid][1] = dy * inv; y1l[tid][2] = dz * inv;
        erdl[tid] = erd[ge];
    }
    __syncthreads();

    // ---- bulk-stage src rows of hb into LDS (all loads in flight at once)
    {
        for (int i = tid; i < ETM * 66; i += 256) {
            int e = i / 66, j = i - e * 66;
            bf16x8 v = *(const bf16x8*)&hb[(size_t)srcl[e] * FEAT + j * 8];
            *(bf16x8*)&hsl[e * HSP + j * 8] = v;
        }
        for (int i = tid; i < ETM * VDIM; i += 256) {
            int e = i >> 5, c = i & 31;
            svl[i] = f2bf(sv[(size_t)srcl[e] * VDIM + c]);
        }
    }

    // ---- stage misc features (k<60, padded to 64) as bf16 into As (alias of wl)
    {
        const int k = tid & 63;
        const int ebase = tid >> 6;
        #pragma unroll
        for (int it = 0; it < 4; ++it) {
            int e = it * 4 + ebase;
            float de = distl[e];
            float v;
            if (k >= 60) v = 0.f;
            else if (k < 16) { float x = (de - (float)k * (10.f/15.f)) * 1.6f; v = expf(-x*x); }
            else if (k < 32) v = etype_emb[itype[e]*16 + (k-16)];
            else if (k < 40) v = btype_emb[ibt[e]*8 + (k-32)];
            else if (k < 44) v = bconj_emb[ibc[e]*4 + (k-40)];
            else if (k < 48) v = bring_emb[ibr[e]*4 + (k-44)];
            else if (k < 52) v = bstereo_emb[ibs[e]*4 + (k-48)];
            else {
                int j = k - 52;
                float dd = de - erdl[e];
                float hr = erdl[e] > 0.f ? 1.f : 0.f;
                v = fabsf(dd)*refW[j] + dd*refW[8+j] + hr*refW[16+j] + refb[j];
            }
            As[e * AP1 + k] = f2bf(v);
        }
    }
    __syncthreads();

    // ---- tiny MFMA GEMM (misc, reads As) + srcdst gathers into registers
    const int wid = tid >> 6, lane = tid & 63;
    const int lr = lane & 15, lkb = (lane >> 4) << 3;
    const int nt0 = wid * 6;                  // 25 tiles / 4 waves, 7 each (overlap dup)
    const int rbase = (lane >> 4) << 2;
    {
        f32x4 acc[7];
        #pragma unroll
        for (int t = 0; t < 7; ++t) acc[t] = (f32x4){0.f, 0.f, 0.f, 0.f};

        #pragma unroll
        for (int ks = 0; ks < 2; ++ks) {
            int kb = ks * 32 + lkb;
            bf16x8 a0 = *(const bf16x8*)&As[lr * AP1 + kb];
            #pragma unroll
            for (int t = 0; t < 7; ++t) {
                bf16x8 b = *(const bf16x8*)&Wt1[(size_t)((nt0 + t) * 16 + lr) * 64 + kb];
                acc[t] = __builtin_amdgcn_mfma_f32_16x16x32_bf16(a0, b, acc[t], 0, 0, 0);
            }
        }
        int se[4], de_[4];
        #pragma unroll
        for (int r = 0; r < 4; ++r) { se[r] = srcl[rbase + r]; de_[r] = dstl[rbase + r]; }
        float addv[7][4];
        #pragma unroll
        for (int t = 0; t < 7; ++t) {
            const int col = (nt0 + t) * 16 + lr;
            #pragma unroll
            for (int r = 0; r < 4; ++r) {
                addv[t][r] = bf2f(srcdst[(size_t)se[r] * 800 + col])
                           + bf2f(srcdst[(size_t)de_[r] * 800 + 400 + col]);
            }
        }
        __syncthreads();   // As (aliased in wl) now dead; safe to overwrite wl
        #pragma unroll
        for (int t = 0; t < 7; ++t) {
            const int col = (nt0 + t) * 16 + lr;
            #pragma unroll
            for (int r = 0; r < 4; ++r)
                wl[(rbase + r) * WLP + col] = f2bf(acc[t][r] + addv[t][r]);
        }
    }
    __syncthreads();

    // ---- messages with run-accumulation (edges sorted by dst); all operands in LDS
    {
        int cls = 0, cc = 0, ii = 0, ia = 0, ib = 0, hoff = 0, wB1 = 0, wB2 = 0;
        if (tid < 96)       { cls = 0; cc = tid / 3;        ii = tid % 3;        hoff = 256 + tid; wB1 = 256 + cc; wB2 = 288 + cc; }
        else if (tid < 192) { int j = tid - 96; cls = 1; cc = j / 3; ii = j % 3; hoff = 352 + j;   wB1 = 320 + cc; wB2 = 352 + cc; }
        else                { int j = tid - 192; cls = 2; cc = j / 5;            hoff = 448 + j;   wB1 = 384 + cc; }
        ia = (ii + 1) % 3; ib = (ii + 2) % 3;

        const bool hasC = tid < 16;
        const int jC = 64 + tid;          // l2 channel slot 64..79
        const int hoffC = 448 + jC;       // feature offset 512..527
        const int wC = 384 + jC / 5;

        float accA = 0.f, accB = 0.f, accC = 0.f;
        for (int e = 0; e < ETM; ++e) {
            const unsigned short* hs = &hsl[e * HSP];
            accA = fmaf(bf2f(wl[e * WLP + tid]), bf2f(hs[tid]), accA);
            float m;
            if (cls == 0) {
                float wv1 = bf2f(wl[e * WLP + wB1]), wsv = bf2f(wl[e * WLP + wB2]);
                m = wv1 * bf2f(hs[hoff]) + wsv * bf2f(svl[e * VDIM + cc]) * y1l[e][ii];
            } else if (cls == 1) {
                float wv2 = bf2f(wl[e * WLP + wB1]), wcx = bf2f(wl[e * WLP + wB2]);
                float va = bf2f(hs[256 + cc * 3 + ia]), vb = bf2f(hs[256 + cc * 3 + ib]);
                m = wv2 * bf2f(hs[hoff]) + wcx * (va * y1l[e][ib] - vb * y1l[e][ia]);
            } else {
                m = bf2f(wl[e * WLP + wB1]) * bf2f(hs[hoff]);
            }
            accB += m;
            if (hasC) accC = fmaf(bf2f(wl[e * WLP + wC]), bf2f(hs[hoffC]), accC);

            bool fl = (e == ETM - 1) || (dstl[e + 1] != dstl[e]);
            if (fl) {
                int d = dstl[e];
                atomicAdd(&agg[(size_t)d * FEAT + tid], accA);
                atomicAdd(&agg[(size_t)d * FEAT + 256 + tid], accB);
                if (hasC) atomicAdd(&agg[(size_t)d * FEAT + hoffC], accC);
                accA = 0.f; accB = 0.f; accC = 0.f;
            }
        }
    }
}

// ================================================================ proj kernel: us = silu(agg_s*DEG_INV @ proj_s) (bf16 out)
__global__ __launch_bounds__(256) void proj_kernel(
    const float* __restrict__ agg, const unsigned short* __restrict__ Ps,
    unsigned short* __restrict__ us_buf)
{
    __shared__ unsigned short As3[32 * AP3];
    const int tid = threadIdx.x;
    const int n0 = blockIdx.x * 32;

    for (int e = 0; e < 32; ++e) {
        int n = n0 + e;
        float v = (n < NN) ? agg[(size_t)n * FEAT + tid] * DEG_INV : 0.f;
        As3[e * AP3 + tid] = f2bf(v);
    }
    __syncthreads();

    const int wid = tid >> 6, lane = tid & 63;
    const int lr = lane & 15, lkb = (lane >> 4) << 3;
    const int rbase = (lane >> 4) << 2;
    const int nt0 = wid * 4;          // 16 tiles over 4 waves

    f32x4 acc[2][4];
    #pragma unroll
    for (int m = 0; m < 2; ++m)
        #pragma unroll
        for (int t = 0; t < 4; ++t) acc[m][t] = (f32x4){0.f, 0.f, 0.f, 0.f};

    for (int ks = 0; ks < 8; ++ks) {
        int kb = ks * 32 + lkb;
        bf16x8 a0 = *(const bf16x8*)&As3[lr * AP3 + kb];
        bf16x8 a1 = *(const bf16x8*)&As3[(16 + lr) * AP3 + kb];
        #pragma unroll
        for (int t = 0; t < 4; ++t) {
            bf16x8 b = *(const bf16x8*)&Ps[(size_t)((nt0 + t) * 16 + lr) * 256 + kb];
            acc[0][t] = __builtin_amdgcn_mfma_f32_16x16x32_bf16(a0, b, acc[0][t], 0, 0, 0);
            acc[1][t] = __builtin_amdgcn_mfma_f32_16x16x32_bf16(a1, b, acc[1][t], 0, 0, 0);
        }
    }
    #pragma unroll
    for (int t = 0; t < 4; ++t) {
        int col = (nt0 + t) * 16 + lr;
        #pragma unroll
        for (int m = 0; m < 2; ++m) {
            #pragma unroll
            for (int r = 0; r < 4; ++r) {
                int n = n0 + m * 16 + rbase + r;
                if (n < NN) {
                    float x = acc[m][t][r];
                    us_buf[(size_t)n * SDIM + col] = f2bf(x / (1.f + expf(-x)));
                }
            }
        }
    }
}

// ================================================================ node kernel: wave-per-node, 4 nodes/block
__global__ __launch_bounds__(256) void node_kernel(
    const float* __restrict__ hcur, const float* __restrict__ ada_buf,
    const float* __restrict__ agg, const unsigned short* __restrict__ us_buf,
    const float* __restrict__ pv1, const float* __restrict__ pv2,
    const float* __restrict__ pl2,
    float* __restrict__ hnext, unsigned short* __restrict__ hbnext)
{
    __shared__ float plv1[VDIM * VDIM];
    __shared__ float plv2[VDIM * VDIM];
    __shared__ float pll2[L2DIM * L2DIM];
    __shared__ float avl[4][272];

    const int tid = threadIdx.x;
    for (int i = tid; i < VDIM * VDIM; i += 256) { plv1[i] = pv1[i]; plv2[i] = pv2[i]; }
    if (tid < L2DIM * L2DIM) pll2[tid] = pl2[tid];

    const int w = tid >> 6, lane = tid & 63;
    const int n = blockIdx.x * 4 + w;
    const size_t nb = (size_t)n * FEAT;
    const size_t na = (size_t)n * ADA;

    for (int i = lane; i < 272; i += 64) avl[w][i] = agg[nb + 256 + i] * DEG_INV;
    __syncthreads();

    // ---- s: LayerNorm with ada scale/shift
    float snv[4];
    float ssum = 0.f, ssq = 0.f;
    #pragma unroll
    for (int j = 0; j < 4; ++j) {
        int c = lane + 64 * j;
        float v = hcur[nb + c] + bf2f(us_buf[(size_t)n * SDIM + c]);
        snv[j] = v; ssum += v; ssq += v * v;
    }
    #pragma unroll
    for (int off = 32; off > 0; off >>= 1) {
        ssum += __shfl_xor(ssum, off, 64);
        ssq  += __shfl_xor(ssq, off, 64);
    }
    float mu = ssum * (1.f / SDIM);
    float var = ssq * (1.f / SDIM) - mu * mu;
    float rstd = rsqrtf(var + 1e-5f);
    #pragma unroll
    for (int j = 0; j < 4; ++j) {
        int c = lane + 64 * j;
        float o = (snv[j] - mu) * rstd * (1.f + ada_buf[na + c]) + ada_buf[na + SDIM + c];
        hnext[nb + c] = o;
        if (hbnext) hbnext[nb + c] = f2bf(o);
    }

    // ---- v1o / v1e / l2 projections + residual + vnorms
    float vb[5];
    float S1 = 0.f, S2 = 0.f, S3 = 0.f;
    #pragma unroll
    for (int j = 0; j < 5; ++j) {
        int c = (j < 4) ? (lane + 64 * j) : (256 + lane);
        bool ok = (j < 4) || (lane < 16);
        float val = 0.f;
        if (ok) {
            if (c < 96) {
                int d = c / 3, i = c - 3 * d;
                float a = 0.f;
                #pragma unroll
                for (int k = 0; k < VDIM; ++k) a = fmaf(avl[w][k*3 + i], plv1[k * VDIM + d], a);
                val = hcur[nb + SDIM + c] + a;
                S1 += val * val;
            } else if (c < 192) {
                int c2 = c - 96;
                int d = c2 / 3, i = c2 - 3 * d;
                float a = 0.f;
                #pragma unroll
                for (int k = 0; k < VDIM; ++k) a = fmaf(avl[w][96 + k*3 + i], plv2[k * VDIM + d], a);
                val = hcur[nb + SDIM + c] + a;
                S2 += val * val;
            } else {
                int c2 = c - 192;
                int d = c2 / 5, i = c2 - 5 * d;
                float a = 0.f;
                #pragma unroll
                for (int k = 0; k < L2DIM; ++k) a = fmaf(avl[w][192 + k*5 + i], pll2[k * L2DIM + d], a);
                val = hcur[nb + SDIM + c] + a;
                S3 += val * val;
            }
        }
        vb[j] = val;
    }
    #pragma unroll
    for (int off = 32; off > 0; off >>= 1) {
        S1 += __shfl_xor(S1, off, 64);
        S2 += __shfl_xor(S2, off, 64);
        S3 += __shfl_xor(S3, off, 64);
    }
    float r1 = rsqrtf(S1 * (1.f / VDIM) + 1e-5f);
    float r2 = rsqrtf(S2 * (1.f / VDIM) + 1e-5f);
    float r3 = rsqrtf(S3 * (1.f / L2DIM) + 1e-5f);

    #pragma unroll
    for (int j = 0; j < 5; ++j) {
        int c = (j < 4) ? (lane + 64 * j) : (256 + lane);
        bool ok = (j < 4) || (lane < 16);
        if (ok) {
            float o;
            if (c < 96) {
                int d = c / 3;
                o = vb[j] * r1 * (1.f + ada_buf[na + 2*SDIM + d]);
            } else if (c < 192) {
                int d = (c - 96) / 3;
                o = vb[j] * r2 * (1.f + ada_buf[na + 2*SDIM + VDIM + d]);
            } else {
                int d = (c - 192) / 5;
                o = vb[j] * r3 * (1.f + ada_buf[na + 2*SDIM + 2*VDIM + d]);
            }
            hnext[nb + SDIM + c] = o;
            if (hbnext) hbnext[nb + SDIM + c] = f2bf(o);
        }
    }
}

// ================================================================ launch
extern "C" void kernel_launch(void* const* d_in, const int* in_sizes, int n_in,
                              void* d_out, int out_size, void* d_ws, size_t ws_size,
                              hipStream_t stream) {
    const float* h_in   = (const float*)d_in[0];
    const float* coords = (const float*)d_in[1];
    const float* erd    = (const float*)d_in[2];
    const float* t_emb  = (const float*)d_in[3];
    const float* etype_emb   = (const float*)d_in[4];
    const float* btype_emb   = (const float*)d_in[5];
    const float* bconj_emb   = (const float*)d_in[6];
    const float* bring_emb   = (const float*)d_in[7];
    const float* bstereo_emb = (const float*)d_in[8];
    const float* refW   = (const float*)d_in[9];
    const float* refb   = (const float*)d_in[10];
    const float* edgeW  = (const float*)d_in[11];
    const float* edgeb  = (const float*)d_in[12];
    const float* svW    = (const float*)d_in[13];
    const float* proj_s = (const float*)d_in[14];
    const float* proj_v1= (const float*)d_in[15];
    const float* proj_v2= (const float*)d_in[16];
    const float* proj_l2= (const float*)d_in[17];
    const float* adaW   = (const float*)d_in[18];
    const float* adab   = (const float*)d_in[19];
    const int* eidx     = (const int*)d_in[20];
    const int* etype    = (const int*)d_in[21];
    const int* ebt      = (const int*)d_in[22];
    const int* ebc      = (const int*)d_in[23];
    const int* ebr      = (const int*)d_in[24];
    const int* ebs      = (const int*)d_in[25];

    float* ws_f     = (float*)d_ws;
    float* sv       = ws_f;                           // N*32
    float* agg      = sv + (size_t)NN * VDIM;         // N*528
    float* h1       = agg + (size_t)NN * FEAT;        // N*528
    float* ada_buf  = h1 + (size_t)NN * FEAT;         // N*592
    float* us_f     = ada_buf + (size_t)NN * ADA;     // N*256 slot (used as bf16)
    unsigned short* us_buf = (unsigned short*)us_f;
    unsigned short* srcdst = (unsigned short*)(us_f + (size_t)NN * SDIM);    // N*800
    unsigned short* hb     = srcdst + (size_t)NN * 800;                      // N*528
    unsigned short* Wt1    = hb + (size_t)NN * FEAT;                         // 400*64
    unsigned short* Bn     = Wt1 + (size_t)WOUT * 64;                        // 800*384
    unsigned short* Ba     = Bn + (size_t)800 * 384;                         // 592*128
    unsigned short* Bsv    = Ba + (size_t)ADA * 128;                         // 32*256
    unsigned short* Ps     = Bsv + (size_t)VDIM * 256;                       // 256*256
    int* cnt    = (int*)(Ps + (size_t)SDIM * 256);    // N
    int* cursor = cnt + NN;                           // N
    int* perm   = cursor + NN;                        // E

    // ---- sort edges by dst (once; reused by both layers)
    hipMemsetAsync(cnt, 0, NN * sizeof(int), stream);
    hist_kernel<<<(NE + 255) / 256, 256, 0, stream>>>(eidx, cnt);
    scan_kernel<<<1, 1024, 0, stream>>>(cnt, cursor);
    scatter_kernel<<<(NE + 255) / 256, 256, 0, stream>>>(eidx, cursor, perm);
    hb_kernel<<<(NN * FEAT / 4 + 255) / 256, 256, 0, stream>>>(h_in, hb);

    for (int l = 0; l < 2; ++l) {
        const float* hcur = (l == 0) ? h_in : h1;
        float* hnext      = (l == 0) ? h1 : (float*)d_out;
        const float* W    = edgeW + (size_t)l * 700 * WOUT;

        hipMemsetAsync(agg, 0, (size_t)NN * FEAT * sizeof(float), stream);
        prep_kernel<<<(O5 + 255) / 256, 256, 0, stream>>>(
            W, adaW + (size_t)l * TDIM * ADA, svW + (size_t)l * SDIM * VDIM,
            proj_s + (size_t)l * SDIM * SDIM, Wt1, Bn, Ba, Bsv, Ps);
        nodeproj_kernel<<<(NN + 31) / 32, 256, 0, stream>>>(
            hb, t_emb, Bn, Ba, Bsv, edgeb + l * WOUT, adab + l * ADA,
            srcdst, ada_buf, sv);
        edge_kernel<<<NE / ETM, 256, 0, stream>>>(
            hb, coords, erd, sv, Wt1, srcdst, perm,
            eidx, etype, ebt, ebc, ebr, ebs,
            etype_emb + l * 144, btype_emb + l * 48, bconj_emb + l * 12,
            bring_emb + l * 12, bstereo_emb + l * 20,
            refW + l * 24, refb + l * 8,
            agg);
        proj_kernel<<<(NN + 31) / 32, 256, 0, stream>>>(agg, Ps, us_buf);
        node_kernel<<<NN / 4, 256, 0, stream>>>(
            hcur, ada_buf, agg, us_buf,
            proj_v1 + l * VDIM * VDIM, proj_v2 + l * VDIM * VDIM,
            proj_l2 + l * L2DIM * L2DIM,
            hnext, (l == 0) ? hb : (unsigned short*)nullptr);
    }
}

// Round 12
// 886.086 us; speedup vs baseline: 1.0096x; 1.0096x over previous
//
#include <hip/hip_runtime.h>
#include <math.h>

#define NN 10000
#define NE 160000
#define SDIM 256
#define VDIM 32
#define L2DIM 16
#define TDIM 128
#define FEAT 528      // S + 3V + 3V + 5*L2
#define WOUT 400      // S + 4V + L2
#define ADA 592       // 2S+2V+L2
#define DEG_INV 0.25f

#define ETM 16        // edges per block
#define WLP 404       // w LDS stride (bf16 elems) -- 404: rows 4 apart land on distinct banks
#define AP1 72        // misc A stride (bf16) -- aliased into wl
#define AP2 392       // nodeproj A stride (bf16)
#define AP3 264       // proj kernel A stride (bf16)
#define HSP 536       // staged h row stride (bf16 elems) -- padded, bank-safe

typedef short bf16x8 __attribute__((ext_vector_type(8)));
typedef float f32x4 __attribute__((ext_vector_type(4)));

__device__ __forceinline__ unsigned short f2bf(float f) {
    unsigned int u = __float_as_uint(f);
    u += 0x7fffu + ((u >> 16) & 1u);      // round-to-nearest-even
    return (unsigned short)(u >> 16);
}
__device__ __forceinline__ float bf2f(unsigned short b) {
    return __uint_as_float(((unsigned int)b) << 16);
}

// ================================================================ sort by dst
__global__ __launch_bounds__(256) void hist_kernel(const int* __restrict__ eidx,
                                                   int* __restrict__ cnt) {
    int e = blockIdx.x * 256 + threadIdx.x;
    if (e < NE) atomicAdd(&cnt[eidx[NE + e]], 1);
}

__global__ __launch_bounds__(1024) void scan_kernel(const int* __restrict__ cnt,
                                                    int* __restrict__ cursor) {
    __shared__ int sc[1024];
    int tid = threadIdx.x;
    int base = tid * 10;
    int loc[10];
    int s = 0;
    if (base < NN) {
        #pragma unroll
        for (int j = 0; j < 10; ++j) { loc[j] = cnt[base + j]; s += loc[j]; }
    }
    sc[tid] = s;
    __syncthreads();
    for (int off = 1; off < 1024; off <<= 1) {
        int v = sc[tid];
        int add = (tid >= off) ? sc[tid - off] : 0;
        __syncthreads();
        sc[tid] = v + add;
        __syncthreads();
    }
    int run = sc[tid] - s;   // exclusive prefix
    if (base < NN) {
        #pragma unroll
        for (int j = 0; j < 10; ++j) { cursor[base + j] = run; run += loc[j]; }
    }
}

__global__ __launch_bounds__(256) void scatter_kernel(const int* __restrict__ eidx,
                                                      int* __restrict__ cursor,
                                                      int* __restrict__ perm) {
    int e = blockIdx.x * 256 + threadIdx.x;
    if (e < NE) {
        int d = eidx[NE + e];
        int p = atomicAdd(&cursor[d], 1);
        perm[p] = e;
    }
}

// ================================================================ fused weight prep
// Wt1[400][64], Bn[800][384], Ba[592][128], Bsv[32][256], Ps[256][256]
#define O1 25600
#define O2 332800
#define O3 408576
#define O4 416768
#define O5 482304
__global__ __launch_bounds__(256) void prep_kernel(
    const float* __restrict__ W, const float* __restrict__ adaW,
    const float* __restrict__ svW, const float* __restrict__ projs,
    unsigned short* __restrict__ Wt1, unsigned short* __restrict__ Bn,
    unsigned short* __restrict__ Ba, unsigned short* __restrict__ Bsv,
    unsigned short* __restrict__ Ps)
{
    int idx = blockIdx.x * 256 + threadIdx.x;
    if (idx < O1) {
        int c = idx >> 6, k = idx & 63;
        float v = (k < 60) ? W[(size_t)k * WOUT + c] : 0.f;
        Wt1[idx] = f2bf(v);
    } else if (idx < O2) {
        int i = idx - O1;
        int c = i / 384, k = i - c * 384;
        float v;
        if (c < WOUT) v = (k < 256) ? W[(size_t)(60 + k) * WOUT + c] : 0.f;
        else {
            int c2 = c - WOUT;
            v = (k < 256) ? W[(size_t)(316 + k) * WOUT + c2]
                          : W[(size_t)(572 + (k - 256)) * WOUT + c2];
        }
        Bn[i] = f2bf(v);
    } else if (idx < O3) {
        int i = idx - O2;
        int c = i >> 7, k = i & 127;
        Ba[i] = f2bf(adaW[(size_t)k * ADA + c]);
    } else if (idx < O4) {
        int i = idx - O3;
        int c = i >> 8, k = i & 255;
        Bsv[i] = f2bf(svW[(size_t)k * VDIM + c]);
    } else if (idx < O5) {
        int i = idx - O4;
        int c = i >> 8, k = i & 255;
        Ps[i] = f2bf(projs[(size_t)k * SDIM + c]);
    }
}

// ================================================================ hb = bf16(h) (input layer only)
struct us4 { unsigned short x, y, z, w; };
__global__ __launch_bounds__(256) void hb_kernel(const float* __restrict__ h,
                                                 unsigned short* __restrict__ hb) {
    int i = blockIdx.x * 256 + threadIdx.x;
    if (i >= NN * FEAT / 4) return;
    float4 v = ((const float4*)h)[i];
    us4 o;
    o.x = f2bf(v.x); o.y = f2bf(v.y); o.z = f2bf(v.z); o.w = f2bf(v.w);
    ((us4*)hb)[i] = o;
}

// ================================================================ nodeproj: srcdst (bf16) + ada (f32) + sv (f32)
__global__ __launch_bounds__(256) void nodeproj_kernel(
    const unsigned short* __restrict__ hb, const float* __restrict__ t_emb,
    const unsigned short* __restrict__ Bn, const unsigned short* __restrict__ Ba,
    const unsigned short* __restrict__ Bsv,
    const float* __restrict__ edge_b, const float* __restrict__ adab,
    unsigned short* __restrict__ srcdst, float* __restrict__ ada_out,
    float* __restrict__ sv)
{
    __shared__ unsigned short As2[32 * AP2];
    const int tid = threadIdx.x;
    const int n0 = blockIdx.x * 32;

    for (int e = 0; e < 32; ++e) {
        int n = n0 + e;
        As2[e * AP2 + tid] = (n < NN) ? hb[(size_t)n * FEAT + tid] : 0;
        if (tid < 128) {
            float v1 = (n < NN) ? t_emb[(size_t)n * TDIM + tid] : 0.f;
            As2[e * AP2 + 256 + tid] = f2bf(v1);
        }
    }
    __syncthreads();

    const int wid = tid >> 6, lane = tid & 63;
    const int lr = lane & 15, lkb = (lane >> 4) << 3;
    const int rbase = (lane >> 4) << 2;

    // ---- main: 50 tiles, K=384
    {
        const int nt0 = wid * 13;
        f32x4 acc[2][13];
        #pragma unroll
        for (int m = 0; m < 2; ++m)
            #pragma unroll
            for (int t = 0; t < 13; ++t) acc[m][t] = (f32x4){0.f, 0.f, 0.f, 0.f};

        for (int ks = 0; ks < 12; ++ks) {
            int kb = ks * 32 + lkb;
            bf16x8 a0 = *(const bf16x8*)&As2[lr * AP2 + kb];
            bf16x8 a1 = *(const bf16x8*)&As2[(16 + lr) * AP2 + kb];
            #pragma unroll
            for (int t = 0; t < 13; ++t) {
                int tile = nt0 + t;
                if (tile < 50) {
                    bf16x8 b = *(const bf16x8*)&Bn[(size_t)(tile * 16 + lr) * 384 + kb];
                    acc[0][t] = __builtin_amdgcn_mfma_f32_16x16x32_bf16(a0, b, acc[0][t], 0, 0, 0);
                    acc[1][t] = __builtin_amdgcn_mfma_f32_16x16x32_bf16(a1, b, acc[1][t], 0, 0, 0);
                }
            }
        }
        #pragma unroll
        for (int t = 0; t < 13; ++t) {
            int tile = nt0 + t;
            if (tile < 50) {
                int col = tile * 16 + lr;
                float badd = (col >= WOUT) ? edge_b[col - WOUT] : 0.f;
                #pragma unroll
                for (int m = 0; m < 2; ++m) {
                    #pragma unroll
                    for (int r = 0; r < 4; ++r) {
                        int n = n0 + m * 16 + rbase + r;
                        if (n < NN) srcdst[(size_t)n * 800 + col] = f2bf(acc[m][t][r] + badd);
                    }
                }
            }
        }
    }

    // ---- ada: 37 tiles, K=128
    {
        const int nt0a = wid * 9;
        f32x4 acc2[2][10];
        #pragma unroll
        for (int m = 0; m < 2; ++m)
            #pragma unroll
            for (int t = 0; t < 10; ++t) acc2[m][t] = (f32x4){0.f, 0.f, 0.f, 0.f};

        for (int ks = 0; ks < 4; ++ks) {
            int kin = ks * 32 + lkb;
            bf16x8 a0 = *(const bf16x8*)&As2[lr * AP2 + 256 + kin];
            bf16x8 a1 = *(const bf16x8*)&As2[(16 + lr) * AP2 + 256 + kin];
            #pragma unroll
            for (int t = 0; t < 10; ++t) {
                int tile = nt0a + t;
                if (tile < 37) {
                    bf16x8 b = *(const bf16x8*)&Ba[(size_t)(tile * 16 + lr) * 128 + kin];
                    acc2[0][t] = __builtin_amdgcn_mfma_f32_16x16x32_bf16(a0, b, acc2[0][t], 0, 0, 0);
                    acc2[1][t] = __builtin_amdgcn_mfma_f32_16x16x32_bf16(a1, b, acc2[1][t], 0, 0, 0);
                }
            }
        }
        #pragma unroll
        for (int t = 0; t < 10; ++t) {
            int tile = nt0a + t;
            if (tile < 37) {
                int col = tile * 16 + lr;
                float badd = adab[col];
                #pragma unroll
                for (int m = 0; m < 2; ++m) {
                    #pragma unroll
                    for (int r = 0; r < 4; ++r) {
                        int n = n0 + m * 16 + rbase + r;
                        if (n < NN) ada_out[(size_t)n * ADA + col] = acc2[m][t][r] + badd;
                    }
                }
            }
        }
    }

    // ---- sv: 2 tiles (waves 0,1), K=256
    if (wid < 2) {
        f32x4 accs[2];
        accs[0] = (f32x4){0.f, 0.f, 0.f, 0.f};
        accs[1] = (f32x4){0.f, 0.f, 0.f, 0.f};
        for (int ks = 0; ks < 8; ++ks) {
            int kb = ks * 32 + lkb;
            bf16x8 a0 = *(const bf16x8*)&As2[lr * AP2 + kb];
            bf16x8 a1 = *(const bf16x8*)&As2[(16 + lr) * AP2 + kb];
            bf16x8 b = *(const bf16x8*)&Bsv[(size_t)(wid * 16 + lr) * 256 + kb];
            accs[0] = __builtin_amdgcn_mfma_f32_16x16x32_bf16(a0, b, accs[0], 0, 0, 0);
            accs[1] = __builtin_amdgcn_mfma_f32_16x16x32_bf16(a1, b, accs[1], 0, 0, 0);
        }
        int col = wid * 16 + lr;
        #pragma unroll
        for (int m = 0; m < 2; ++m) {
            #pragma unroll
            for (int r = 0; r < 4; ++r) {
                int n = n0 + m * 16 + rbase + r;
                if (n < NN) sv[(size_t)n * VDIM + col] = accs[m][r];
            }
        }
    }
}

// ================================================================ edge kernel (diet + bank-safe strides: 5 blocks/CU)
__global__ __launch_bounds__(256) void edge_kernel(
    const unsigned short* __restrict__ hb, const float* __restrict__ coords,
    const float* __restrict__ erd, const float* __restrict__ sv,
    const unsigned short* __restrict__ Wt1, const unsigned short* __restrict__ srcdst,
    const int* __restrict__ perm, const int* __restrict__ eidx,
    const int* __restrict__ etype, const int* __restrict__ ebt,
    const int* __restrict__ ebc, const int* __restrict__ ebr,
    const int* __restrict__ ebs,
    const float* __restrict__ etype_emb, const float* __restrict__ btype_emb,
    const float* __restrict__ bconj_emb, const float* __restrict__ bring_emb,
    const float* __restrict__ bstereo_emb,
    const float* __restrict__ refW, const float* __restrict__ refb,
    float* __restrict__ agg)
{
    __shared__ unsigned short wl[ETM * WLP];     // 12.9 KB (bf16 w; front aliased as As)
    __shared__ unsigned short hsl[ETM * HSP];    // 17.2 KB staged src rows
    __shared__ unsigned short svl[ETM * VDIM];   // 1 KB staged sv rows (bf16)
    __shared__ int srcl[ETM], dstl[ETM];
    __shared__ int itype[ETM], ibt[ETM], ibc[ETM], ibr[ETM], ibs[ETM];
    __shared__ float distl[ETM], erdl[ETM], y1l[ETM][3];

    unsigned short* As = wl;   // alias: As dead before wl is written (barrier between)

    const int tid = threadIdx.x;
    const int bid = (blockIdx.x & 7) * 1250 + (blockIdx.x >> 3);   // XCD swizzle
    const int e0 = bid * ETM;

    if (tid < ETM) {
        int ge = perm[e0 + tid];
        int s = eidx[ge], d = eidx[NE + ge];
        srcl[tid] = s; dstl[tid] = d;
        itype[tid] = etype[ge]; ibt[tid] = ebt[ge]; ibc[tid] = ebc[ge];
        ibr[tid] = ebr[ge]; ibs[tid] = ebs[ge];
        float dx = coords[d*3+0] - coords[s*3+0];
        float dy = coords[d*3+1] - coords[s*3+1];
        float dz = coords[d*3+2] - coords[s*3+2];
        float dist = sqrtf(dx*dx + dy*dy + dz*dz);
        distl[tid] = dist;
        float inv = 1.f / (dist + 1e-8f);
        y1l[tid][0] = dx * inv; y1l[tid][1] = dy * inv; y1l[tid][2] = dz * inv;
        erdl[tid] = erd[ge];
    }
    __syncthreads();

    // ---- bulk-stage src rows of hb into LDS (all loads in flight at once)
    {
        for (int i = tid; i < ETM * 66; i += 256) {
            int e = i / 66, j = i - e * 66;
            bf16x8 v = *(const bf16x8*)&hb[(size_t)srcl[e] * FEAT + j * 8];
            *(bf16x8*)&hsl[e * HSP + j * 8] = v;
        }
        for (int i = tid; i < ETM * VDIM; i += 256) {
            int e = i >> 5, c = i & 31;
            svl[i] = f2bf(sv[(size_t)srcl[e] * VDIM + c]);
        }
    }

    // ---- stage misc features (k<60, padded to 64) as bf16 into As (alias of wl)
    {
        const int k = tid & 63;
        const int ebase = tid >> 6;
        #pragma unroll
        for (int it = 0; it < 4; ++it) {
            int e = it * 4 + ebase;
            float de = distl[e];
            float v;
            if (k >= 60) v = 0.f;
            else if (k < 16) { float x = (de - (float)k * (10.f/15.f)) * 1.6f; v = expf(-x*x); }
            else if (k < 32) v = etype_emb[itype[e]*16 + (k-16)];
            else if (k < 40) v = btype_emb[ibt[e]*8 + (k-32)];
            else if (k < 44) v = bconj_emb[ibc[e]*4 + (k-40)];
            else if (k < 48) v = bring_emb[ibr[e]*4 + (k-44)];
            else if (k < 52) v = bstereo_emb[ibs[e]*4 + (k-48)];
            else {
                int j = k - 52;
                float dd = de - erdl[e];
                float hr = erdl[e] > 0.f ? 1.f : 0.f;
                v = fabsf(dd)*refW[j] + dd*refW[8+j] + hr*refW[16+j] + refb[j];
            }
            As[e * AP1 + k] = f2bf(v);
        }
    }
    __syncthreads();

    // ---- tiny MFMA GEMM (misc, reads As) + srcdst gathers into registers
    const int wid = tid >> 6, lane = tid & 63;
    const int lr = lane & 15, lkb = (lane >> 4) << 3;
    const int nt0 = wid * 6;                  // 25 tiles / 4 waves, 7 each (overlap dup)
    const int rbase = (lane >> 4) << 2;
    {
        f32x4 acc[7];
        #pragma unroll
        for (int t = 0; t < 7; ++t) acc[t] = (f32x4){0.f, 0.f, 0.f, 0.f};

        #pragma unroll
        for (int ks = 0; ks < 2; ++ks) {
            int kb = ks * 32 + lkb;
            bf16x8 a0 = *(const bf16x8*)&As[lr * AP1 + kb];
            #pragma unroll
            for (int t = 0; t < 7; ++t) {
                bf16x8 b = *(const bf16x8*)&Wt1[(size_t)((nt0 + t) * 16 + lr) * 64 + kb];
                acc[t] = __builtin_amdgcn_mfma_f32_16x16x32_bf16(a0, b, acc[t], 0, 0, 0);
            }
        }
        int se[4], de_[4];
        #pragma unroll
        for (int r = 0; r < 4; ++r) { se[r] = srcl[rbase + r]; de_[r] = dstl[rbase + r]; }
        float addv[7][4];
        #pragma unroll
        for (int t = 0; t < 7; ++t) {
            const int col = (nt0 + t) * 16 + lr;
            #pragma unroll
            for (int r = 0; r < 4; ++r) {
                addv[t][r] = bf2f(srcdst[(size_t)se[r] * 800 + col])
                           + bf2f(srcdst[(size_t)de_[r] * 800 + 400 + col]);
            }
        }
        __syncthreads();   // As (aliased in wl) now dead; safe to overwrite wl
        #pragma unroll
        for (int t = 0; t < 7; ++t) {
            const int col = (nt0 + t) * 16 + lr;
            #pragma unroll
            for (int r = 0; r < 4; ++r)
                wl[(rbase + r) * WLP + col] = f2bf(acc[t][r] + addv[t][r]);
        }
    }
    __syncthreads();

    // ---- messages with run-accumulation (edges sorted by dst); all operands in LDS
    {
        int cls = 0, cc = 0, ii = 0, ia = 0, ib = 0, hoff = 0, wB1 = 0, wB2 = 0;
        if (tid < 96)       { cls = 0; cc = tid / 3;        ii = tid % 3;        hoff = 256 + tid; wB1 = 256 + cc; wB2 = 288 + cc; }
        else if (tid < 192) { int j = tid - 96; cls = 1; cc = j / 3; ii = j % 3; hoff = 352 + j;   wB1 = 320 + cc; wB2 = 352 + cc; }
        else                { int j = tid - 192; cls = 2; cc = j / 5;            hoff = 448 + j;   wB1 = 384 + cc; }
        ia = (ii + 1) % 3; ib = (ii + 2) % 3;

        const bool hasC = tid < 16;
        const int jC = 64 + tid;          // l2 channel slot 64..79
        const int hoffC = 448 + jC;       // feature offset 512..527
        const int wC = 384 + jC / 5;

        float accA = 0.f, accB = 0.f, accC = 0.f;
        for (int e = 0; e < ETM; ++e) {
            const unsigned short* hs = &hsl[e * HSP];
            accA = fmaf(bf2f(wl[e * WLP + tid]), bf2f(hs[tid]), accA);
            float m;
            if (cls == 0) {
                float wv1 = bf2f(wl[e * WLP + wB1]), wsv = bf2f(wl[e * WLP + wB2]);
                m = wv1 * bf2f(hs[hoff]) + wsv * bf2f(svl[e * VDIM + cc]) * y1l[e][ii];
            } else if (cls == 1) {
                float wv2 = bf2f(wl[e * WLP + wB1]), wcx = bf2f(wl[e * WLP + wB2]);
                float va = bf2f(hs[256 + cc * 3 + ia]), vb = bf2f(hs[256 + cc * 3 + ib]);
                m = wv2 * bf2f(hs[hoff]) + wcx * (va * y1l[e][ib] - vb * y1l[e][ia]);
            } else {
                m = bf2f(wl[e * WLP + wB1]) * bf2f(hs[hoff]);
            }
            accB += m;
            if (hasC) accC = fmaf(bf2f(wl[e * WLP + wC]), bf2f(hs[hoffC]), accC);

            bool fl = (e == ETM - 1) || (dstl[e + 1] != dstl[e]);
            if (fl) {
                int d = dstl[e];
                atomicAdd(&agg[(size_t)d * FEAT + tid], accA);
                atomicAdd(&agg[(size_t)d * FEAT + 256 + tid], accB);
                if (hasC) atomicAdd(&agg[(size_t)d * FEAT + hoffC], accC);
                accA = 0.f; accB = 0.f; accC = 0.f;
            }
        }
    }
}

// ================================================================ proj kernel: us = silu(agg_s*DEG_INV @ proj_s) (bf16 out)
__global__ __launch_bounds__(256) void proj_kernel(
    const float* __restrict__ agg, const unsigned short* __restrict__ Ps,
    unsigned short* __restrict__ us_buf)
{
    __shared__ unsigned short As3[32 * AP3];
    const int tid = threadIdx.x;
    const int n0 = blockIdx.x * 32;

    for (int e = 0; e < 32; ++e) {
        int n = n0 + e;
        float v = (n < NN) ? agg[(size_t)n * FEAT + tid] * DEG_INV : 0.f;
        As3[e * AP3 + tid] = f2bf(v);
    }
    __syncthreads();

    const int wid = tid >> 6, lane = tid & 63;
    const int lr = lane & 15, lkb = (lane >> 4) << 3;
    const int rbase = (lane >> 4) << 2;
    const int nt0 = wid * 4;          // 16 tiles over 4 waves

    f32x4 acc[2][4];
    #pragma unroll
    for (int m = 0; m < 2; ++m)
        #pragma unroll
        for (int t = 0; t < 4; ++t) acc[m][t] = (f32x4){0.f, 0.f, 0.f, 0.f};

    for (int ks = 0; ks < 8; ++ks) {
        int kb = ks * 32 + lkb;
        bf16x8 a0 = *(const bf16x8*)&As3[lr * AP3 + kb];
        bf16x8 a1 = *(const bf16x8*)&As3[(16 + lr) * AP3 + kb];
        #pragma unroll
        for (int t = 0; t < 4; ++t) {
            bf16x8 b = *(const bf16x8*)&Ps[(size_t)((nt0 + t) * 16 + lr) * 256 + kb];
            acc[0][t] = __builtin_amdgcn_mfma_f32_16x16x32_bf16(a0, b, acc[0][t], 0, 0, 0);
            acc[1][t] = __builtin_amdgcn_mfma_f32_16x16x32_bf16(a1, b, acc[1][t], 0, 0, 0);
        }
    }
    #pragma unroll
    for (int t = 0; t < 4; ++t) {
        int col = (nt0 + t) * 16 + lr;
        #pragma unroll
        for (int m = 0; m < 2; ++m) {
            #pragma unroll
            for (int r = 0; r < 4; ++r) {
                int n = n0 + m * 16 + rbase + r;
                if (n < NN) {
                    float x = acc[m][t][r];
                    us_buf[(size_t)n * SDIM + col] = f2bf(x / (1.f + expf(-x)));
                }
            }
        }
    }
}

// ================================================================ node kernel: wave-per-node, 4 nodes/block
__global__ __launch_bounds__(256) void node_kernel(
    const float* __restrict__ hcur, const float* __restrict__ ada_buf,
    const float* __restrict__ agg, const unsigned short* __restrict__ us_buf,
    const float* __restrict__ pv1, const float* __restrict__ pv2,
    const float* __restrict__ pl2,
    float* __restrict__ hnext, unsigned short* __restrict__ hbnext)
{
    __shared__ float plv1[VDIM * VDIM];
    __shared__ float plv2[VDIM * VDIM];
    __shared__ float pll2[L2DIM * L2DIM];
    __shared__ float avl[4][272];

    const int tid = threadIdx.x;
    for (int i = tid; i < VDIM * VDIM; i += 256) { plv1[i] = pv1[i]; plv2[i] = pv2[i]; }
    if (tid < L2DIM * L2DIM) pll2[tid] = pl2[tid];

    const int w = tid >> 6, lane = tid & 63;
    const int n = blockIdx.x * 4 + w;
    const size_t nb = (size_t)n * FEAT;
    const size_t na = (size_t)n * ADA;

    for (int i = lane; i < 272; i += 64) avl[w][i] = agg[nb + 256 + i] * DEG_INV;
    __syncthreads();

    // ---- s: LayerNorm with ada scale/shift
    float snv[4];
    float ssum = 0.f, ssq = 0.f;
    #pragma unroll
    for (int j = 0; j < 4; ++j) {
        int c = lane + 64 * j;
        float v = hcur[nb + c] + bf2f(us_buf[(size_t)n * SDIM + c]);
        snv[j] = v; ssum += v; ssq += v * v;
    }
    #pragma unroll
    for (int off = 32; off > 0; off >>= 1) {
        ssum += __shfl_xor(ssum, off, 64);
        ssq  += __shfl_xor(ssq, off, 64);
    }
    float mu = ssum * (1.f / SDIM);
    float var = ssq * (1.f / SDIM) - mu * mu;
    float rstd = rsqrtf(var + 1e-5f);
    #pragma unroll
    for (int j = 0; j < 4; ++j) {
        int c = lane + 64 * j;
        float o = (snv[j] - mu) * rstd * (1.f + ada_buf[na + c]) + ada_buf[na + SDIM + c];
        hnext[nb + c] = o;
        if (hbnext) hbnext[nb + c] = f2bf(o);
    }

    // ---- v1o / v1e / l2 projections + residual + vnorms
    float vb[5];
    float S1 = 0.f, S2 = 0.f, S3 = 0.f;
    #pragma unroll
    for (int j = 0; j < 5; ++j) {
        int c = (j < 4) ? (lane + 64 * j) : (256 + lane);
        bool ok = (j < 4) || (lane < 16);
        float val = 0.f;
        if (ok) {
            if (c < 96) {
                int d = c / 3, i = c - 3 * d;
                float a = 0.f;
                #pragma unroll
                for (int k = 0; k < VDIM; ++k) a = fmaf(avl[w][k*3 + i], plv1[k * VDIM + d], a);
                val = hcur[nb + SDIM + c] + a;
                S1 += val * val;
            } else if (c < 192) {
                int c2 = c - 96;
                int d = c2 / 3, i = c2 - 3 * d;
                float a = 0.f;
                #pragma unroll
                for (int k = 0; k < VDIM; ++k) a = fmaf(avl[w][96 + k*3 + i], plv2[k * VDIM + d], a);
                val = hcur[nb + SDIM + c] + a;
                S2 += val * val;
            } else {
                int c2 = c - 192;
                int d = c2 / 5, i = c2 - 5 * d;
                float a = 0.f;
                #pragma unroll
                for (int k = 0; k < L2DIM; ++k) a = fmaf(avl[w][192 + k*5 + i], pll2[k * L2DIM + d], a);
                val = hcur[nb + SDIM + c] + a;
                S3 += val * val;
            }
        }
        vb[j] = val;
    }
    #pragma unroll
    for (int off = 32; off > 0; off >>= 1) {
        S1 += __shfl_xor(S1, off, 64);
        S2 += __shfl_xor(S2, off, 64);
        S3 += __shfl_xor(S3, off, 64);
    }
    float r1 = rsqrtf(S1 * (1.f / VDIM) + 1e-5f);
    float r2 = rsqrtf(S2 * (1.f / VDIM) + 1e-5f);
    float r3 = rsqrtf(S3 * (1.f / L2DIM) + 1e-5f);

    #pragma unroll
    for (int j = 0; j < 5; ++j) {
        int c = (j < 4) ? (lane + 64 * j) : (256 + lane);
        bool ok = (j < 4) || (lane < 16);
        if (ok) {
            float o;
            if (c < 96) {
                int d = c / 3;
                o = vb[j] * r1 * (1.f + ada_buf[na + 2*SDIM + d]);
            } else if (c < 192) {
                int d = (c - 96) / 3;
                o = vb[j] * r2 * (1.f + ada_buf[na + 2*SDIM + VDIM + d]);
            } else {
                int d = (c - 192) / 5;
                o = vb[j] * r3 * (1.f + ada_buf[na + 2*SDIM + 2*VDIM + d]);
            }
            hnext[nb + SDIM + c] = o;
            if (hbnext) hbnext[nb + SDIM + c] = f2bf(o);
        }
    }
}

// ================================================================ launch
extern "C" void kernel_launch(void* const* d_in, const int* in_sizes, int n_in,
                              void* d_out, int out_size, void* d_ws, size_t ws_size,
                              hipStream_t stream) {
    const float* h_in   = (const float*)d_in[0];
    const float* coords = (const float*)d_in[1];
    const float* erd    = (const float*)d_in[2];
    const float* t_emb  = (const float*)d_in[3];
    const float* etype_emb   = (const float*)d_in[4];
    const float* btype_emb   = (const float*)d_in[5];
    const float* bconj_emb   = (const float*)d_in[6];
    const float* bring_emb   = (const float*)d_in[7];
    const float* bstereo_emb = (const float*)d_in[8];
    const float* refW   = (const float*)d_in[9];
    const float* refb   = (const float*)d_in[10];
    const float* edgeW  = (const float*)d_in[11];
    const float* edgeb  = (const float*)d_in[12];
    const float* svW    = (const float*)d_in[13];
    const float* proj_s = (const float*)d_in[14];
    const float* proj_v1= (const float*)d_in[15];
    const float* proj_v2= (const float*)d_in[16];
    const float* proj_l2= (const float*)d_in[17];
    const float* adaW   = (const float*)d_in[18];
    const float* adab   = (const float*)d_in[19];
    const int* eidx     = (const int*)d_in[20];
    const int* etype    = (const int*)d_in[21];
    const int* ebt      = (const int*)d_in[22];
    const int* ebc      = (const int*)d_in[23];
    const int* ebr      = (const int*)d_in[24];
    const int* ebs      = (const int*)d_in[25];

    float* ws_f     = (float*)d_ws;
    float* sv       = ws_f;                           // N*32
    float* agg      = sv + (size_t)NN * VDIM;         // N*528
    float* h1       = agg + (size_t)NN * FEAT;        // N*528
    float* ada_buf  = h1 + (size_t)NN * FEAT;         // N*592
    float* us_f     = ada_buf + (size_t)NN * ADA;     // N*256 slot (used as bf16)
    unsigned short* us_buf = (unsigned short*)us_f;
    unsigned short* srcdst = (unsigned short*)(us_f + (size_t)NN * SDIM);    // N*800
    unsigned short* hb     = srcdst + (size_t)NN * 800;                      // N*528
    unsigned short* Wt1    = hb + (size_t)NN * FEAT;                         // 400*64
    unsigned short* Bn     = Wt1 + (size_t)WOUT * 64;                        // 800*384
    unsigned short* Ba     = Bn + (size_t)800 * 384;                         // 592*128
    unsigned short* Bsv    = Ba + (size_t)ADA * 128;                         // 32*256
    unsigned short* Ps     = Bsv + (size_t)VDIM * 256;                       // 256*256
    int* cnt    = (int*)(Ps + (size_t)SDIM * 256);    // N
    int* cursor = cnt + NN;                           // N
    int* perm   = cursor + NN;                        // E

    // ---- sort edges by dst (once; reused by both layers)
    hipMemsetAsync(cnt, 0, NN * sizeof(int), stream);
    hist_kernel<<<(NE + 255) / 256, 256, 0, stream>>>(eidx, cnt);
    scan_kernel<<<1, 1024, 0, stream>>>(cnt, cursor);
    scatter_kernel<<<(NE + 255) / 256, 256, 0, stream>>>(eidx, cursor, perm);
    hb_kernel<<<(NN * FEAT / 4 + 255) / 256, 256, 0, stream>>>(h_in, hb);

    for (int l = 0; l < 2; ++l) {
        const float* hcur = (l == 0) ? h_in : h1;
        float* hnext      = (l == 0) ? h1 : (float*)d_out;
        const float* W    = edgeW + (size_t)l * 700 * WOUT;

        hipMemsetAsync(agg, 0, (size_t)NN * FEAT * sizeof(float), stream);
        prep_kernel<<<(O5 + 255) / 256, 256, 0, stream>>>(
            W, adaW + (size_t)l * TDIM * ADA, svW + (size_t)l * SDIM * VDIM,
            proj_s + (size_t)l * SDIM * SDIM, Wt1, Bn, Ba, Bsv, Ps);
        nodeproj_kernel<<<(NN + 31) / 32, 256, 0, stream>>>(
            hb, t_emb, Bn, Ba, Bsv, edgeb + l * WOUT, adab + l * ADA,
            srcdst, ada_buf, sv);
        edge_kernel<<<NE / ETM, 256, 0, stream>>>(
            hb, coords, erd, sv, Wt1, srcdst, perm,
            eidx, etype, ebt, ebc, ebr, ebs,
            etype_emb + l * 144, btype_emb + l * 48, bconj_emb + l * 12,
            bring_emb + l * 12, bstereo_emb + l * 20,
            refW + l * 24, refb + l * 8,
            agg);
        proj_kernel<<<(NN + 31) / 32, 256, 0, stream>>>(agg, Ps, us_buf);
        node_kernel<<<NN / 4, 256, 0, stream>>>(
            hcur, ada_buf, agg, us_buf,
            proj_v1 + l * VDIM * VDIM, proj_v2 + l * VDIM * VDIM,
            proj_l2 + l * L2DIM * L2DIM,
            hnext, (l == 0) ? hb : (unsigned short*)nullptr);
    }
}

// Round 13
// 730.356 us; speedup vs baseline: 1.2249x; 1.2132x over previous
//
#include <hip/hip_runtime.h>
#include <math.h>

#define NN 10000
#define NE 160000
#define SDIM 256
#define VDIM 32
#define L2DIM 16
#define TDIM 128
#define FEAT 528      // S + 3V + 3V + 5*L2
#define WOUT 400      // S + 4V + L2
#define ADA 592       // 2S+2V+L2
#define DEG_INV 0.25f

#define ETM 16        // edges per block
#define WLP 404       // w LDS stride (bf16 elems) -- bank-safe
#define AP1 72        // misc A stride (bf16)
#define AP2 392       // nodeproj A stride (bf16)
#define AP3 264       // proj kernel A stride (bf16)
#define HSP 536       // staged h row stride (bf16 elems) -- bank-safe

typedef short bf16x8 __attribute__((ext_vector_type(8)));
typedef float f32x4 __attribute__((ext_vector_type(4)));

__device__ __forceinline__ unsigned short f2bf(float f) {
    unsigned int u = __float_as_uint(f);
    u += 0x7fffu + ((u >> 16) & 1u);      // round-to-nearest-even
    return (unsigned short)(u >> 16);
}
__device__ __forceinline__ float bf2f(unsigned short b) {
    return __uint_as_float(((unsigned int)b) << 16);
}

// ================================================================ sort by dst
__global__ __launch_bounds__(256) void hist_kernel(const int* __restrict__ eidx,
                                                   int* __restrict__ cnt) {
    int e = blockIdx.x * 256 + threadIdx.x;
    if (e < NE) atomicAdd(&cnt[eidx[NE + e]], 1);
}

__global__ __launch_bounds__(1024) void scan_kernel(const int* __restrict__ cnt,
                                                    int* __restrict__ cursor) {
    __shared__ int sc[1024];
    int tid = threadIdx.x;
    int base = tid * 10;
    int loc[10];
    int s = 0;
    if (base < NN) {
        #pragma unroll
        for (int j = 0; j < 10; ++j) { loc[j] = cnt[base + j]; s += loc[j]; }
    }
    sc[tid] = s;
    __syncthreads();
    for (int off = 1; off < 1024; off <<= 1) {
        int v = sc[tid];
        int add = (tid >= off) ? sc[tid - off] : 0;
        __syncthreads();
        sc[tid] = v + add;
        __syncthreads();
    }
    int run = sc[tid] - s;   // exclusive prefix
    if (base < NN) {
        #pragma unroll
        for (int j = 0; j < 10; ++j) { cursor[base + j] = run; run += loc[j]; }
    }
}

__global__ __launch_bounds__(256) void scatter_kernel(const int* __restrict__ eidx,
                                                      int* __restrict__ cursor,
                                                      int* __restrict__ perm) {
    int e = blockIdx.x * 256 + threadIdx.x;
    if (e < NE) {
        int d = eidx[NE + e];
        int p = atomicAdd(&cursor[d], 1);
        perm[p] = e;
    }
}

// ================================================================ fused weight prep
// Wt1[400][64], Bn[800][384], Ba[592][128], Bsv[32][256], Ps[256][256]
#define O1 25600
#define O2 332800
#define O3 408576
#define O4 416768
#define O5 482304
__global__ __launch_bounds__(256) void prep_kernel(
    const float* __restrict__ W, const float* __restrict__ adaW,
    const float* __restrict__ svW, const float* __restrict__ projs,
    unsigned short* __restrict__ Wt1, unsigned short* __restrict__ Bn,
    unsigned short* __restrict__ Ba, unsigned short* __restrict__ Bsv,
    unsigned short* __restrict__ Ps)
{
    int idx = blockIdx.x * 256 + threadIdx.x;
    if (idx < O1) {
        int c = idx >> 6, k = idx & 63;
        float v = (k < 60) ? W[(size_t)k * WOUT + c] : 0.f;
        Wt1[idx] = f2bf(v);
    } else if (idx < O2) {
        int i = idx - O1;
        int c = i / 384, k = i - c * 384;
        float v;
        if (c < WOUT) v = (k < 256) ? W[(size_t)(60 + k) * WOUT + c] : 0.f;
        else {
            int c2 = c - WOUT;
            v = (k < 256) ? W[(size_t)(316 + k) * WOUT + c2]
                          : W[(size_t)(572 + (k - 256)) * WOUT + c2];
        }
        Bn[i] = f2bf(v);
    } else if (idx < O3) {
        int i = idx - O2;
        int c = i >> 7, k = i & 127;
        Ba[i] = f2bf(adaW[(size_t)k * ADA + c]);
    } else if (idx < O4) {
        int i = idx - O3;
        int c = i >> 8, k = i & 255;
        Bsv[i] = f2bf(svW[(size_t)k * VDIM + c]);
    } else if (idx < O5) {
        int i = idx - O4;
        int c = i >> 8, k = i & 255;
        Ps[i] = f2bf(projs[(size_t)k * SDIM + c]);
    }
}

// ================================================================ hb = bf16(h) (input layer only)
struct us4 { unsigned short x, y, z, w; };
__global__ __launch_bounds__(256) void hb_kernel(const float* __restrict__ h,
                                                 unsigned short* __restrict__ hb) {
    int i = blockIdx.x * 256 + threadIdx.x;
    if (i >= NN * FEAT / 4) return;
    float4 v = ((const float4*)h)[i];
    us4 o;
    o.x = f2bf(v.x); o.y = f2bf(v.y); o.z = f2bf(v.z); o.w = f2bf(v.w);
    ((us4*)hb)[i] = o;
}

// ================================================================ nodeproj: srcdst (bf16) + ada (f32) + sv (f32)
__global__ __launch_bounds__(256) void nodeproj_kernel(
    const unsigned short* __restrict__ hb, const float* __restrict__ t_emb,
    const unsigned short* __restrict__ Bn, const unsigned short* __restrict__ Ba,
    const unsigned short* __restrict__ Bsv,
    const float* __restrict__ edge_b, const float* __restrict__ adab,
    unsigned short* __restrict__ srcdst, float* __restrict__ ada_out,
    float* __restrict__ sv)
{
    __shared__ unsigned short As2[32 * AP2];
    const int tid = threadIdx.x;
    const int n0 = blockIdx.x * 32;

    for (int e = 0; e < 32; ++e) {
        int n = n0 + e;
        As2[e * AP2 + tid] = (n < NN) ? hb[(size_t)n * FEAT + tid] : 0;
        if (tid < 128) {
            float v1 = (n < NN) ? t_emb[(size_t)n * TDIM + tid] : 0.f;
            As2[e * AP2 + 256 + tid] = f2bf(v1);
        }
    }
    __syncthreads();

    const int wid = tid >> 6, lane = tid & 63;
    const int lr = lane & 15, lkb = (lane >> 4) << 3;
    const int rbase = (lane >> 4) << 2;

    // ---- main: 50 tiles, K=384
    {
        const int nt0 = wid * 13;
        f32x4 acc[2][13];
        #pragma unroll
        for (int m = 0; m < 2; ++m)
            #pragma unroll
            for (int t = 0; t < 13; ++t) acc[m][t] = (f32x4){0.f, 0.f, 0.f, 0.f};

        for (int ks = 0; ks < 12; ++ks) {
            int kb = ks * 32 + lkb;
            bf16x8 a0 = *(const bf16x8*)&As2[lr * AP2 + kb];
            bf16x8 a1 = *(const bf16x8*)&As2[(16 + lr) * AP2 + kb];
            #pragma unroll
            for (int t = 0; t < 13; ++t) {
                int tile = nt0 + t;
                if (tile < 50) {
                    bf16x8 b = *(const bf16x8*)&Bn[(size_t)(tile * 16 + lr) * 384 + kb];
                    acc[0][t] = __builtin_amdgcn_mfma_f32_16x16x32_bf16(a0, b, acc[0][t], 0, 0, 0);
                    acc[1][t] = __builtin_amdgcn_mfma_f32_16x16x32_bf16(a1, b, acc[1][t], 0, 0, 0);
                }
            }
        }
        #pragma unroll
        for (int t = 0; t < 13; ++t) {
            int tile = nt0 + t;
            if (tile < 50) {
                int col = tile * 16 + lr;
                float badd = (col >= WOUT) ? edge_b[col - WOUT] : 0.f;
                #pragma unroll
                for (int m = 0; m < 2; ++m) {
                    #pragma unroll
                    for (int r = 0; r < 4; ++r) {
                        int n = n0 + m * 16 + rbase + r;
                        if (n < NN) srcdst[(size_t)n * 800 + col] = f2bf(acc[m][t][r] + badd);
                    }
                }
            }
        }
    }

    // ---- ada: 37 tiles, K=128
    {
        const int nt0a = wid * 9;
        f32x4 acc2[2][10];
        #pragma unroll
        for (int m = 0; m < 2; ++m)
            #pragma unroll
            for (int t = 0; t < 10; ++t) acc2[m][t] = (f32x4){0.f, 0.f, 0.f, 0.f};

        for (int ks = 0; ks < 4; ++ks) {
            int kin = ks * 32 + lkb;
            bf16x8 a0 = *(const bf16x8*)&As2[lr * AP2 + 256 + kin];
            bf16x8 a1 = *(const bf16x8*)&As2[(16 + lr) * AP2 + 256 + kin];
            #pragma unroll
            for (int t = 0; t < 10; ++t) {
                int tile = nt0a + t;
                if (tile < 37) {
                    bf16x8 b = *(const bf16x8*)&Ba[(size_t)(tile * 16 + lr) * 128 + kin];
                    acc2[0][t] = __builtin_amdgcn_mfma_f32_16x16x32_bf16(a0, b, acc2[0][t], 0, 0, 0);
                    acc2[1][t] = __builtin_amdgcn_mfma_f32_16x16x32_bf16(a1, b, acc2[1][t], 0, 0, 0);
                }
            }
        }
        #pragma unroll
        for (int t = 0; t < 10; ++t) {
            int tile = nt0a + t;
            if (tile < 37) {
                int col = tile * 16 + lr;
                float badd = adab[col];
                #pragma unroll
                for (int m = 0; m < 2; ++m) {
                    #pragma unroll
                    for (int r = 0; r < 4; ++r) {
                        int n = n0 + m * 16 + rbase + r;
                        if (n < NN) ada_out[(size_t)n * ADA + col] = acc2[m][t][r] + badd;
                    }
                }
            }
        }
    }

    // ---- sv: 2 tiles (waves 0,1), K=256
    if (wid < 2) {
        f32x4 accs[2];
        accs[0] = (f32x4){0.f, 0.f, 0.f, 0.f};
        accs[1] = (f32x4){0.f, 0.f, 0.f, 0.f};
        for (int ks = 0; ks < 8; ++ks) {
            int kb = ks * 32 + lkb;
            bf16x8 a0 = *(const bf16x8*)&As2[lr * AP2 + kb];
            bf16x8 a1 = *(const bf16x8*)&As2[(16 + lr) * AP2 + kb];
            bf16x8 b = *(const bf16x8*)&Bsv[(size_t)(wid * 16 + lr) * 256 + kb];
            accs[0] = __builtin_amdgcn_mfma_f32_16x16x32_bf16(a0, b, accs[0], 0, 0, 0);
            accs[1] = __builtin_amdgcn_mfma_f32_16x16x32_bf16(a1, b, accs[1], 0, 0, 0);
        }
        int col = wid * 16 + lr;
        #pragma unroll
        for (int m = 0; m < 2; ++m) {
            #pragma unroll
            for (int r = 0; r < 4; ++r) {
                int n = n0 + m * 16 + rbase + r;
                if (n < NN) sv[(size_t)n * VDIM + col] = accs[m][r];
            }
        }
    }
}

// ================================================================ edge kernel: round-10 layout, 512 threads / 8 waves
__global__ __launch_bounds__(512) void edge_kernel(
    const unsigned short* __restrict__ hb, const float* __restrict__ coords,
    const float* __restrict__ erd, const float* __restrict__ sv,
    const unsigned short* __restrict__ Wt1, const unsigned short* __restrict__ srcdst,
    const int* __restrict__ perm, const int* __restrict__ eidx,
    const int* __restrict__ etype, const int* __restrict__ ebt,
    const int* __restrict__ ebc, const int* __restrict__ ebr,
    const int* __restrict__ ebs,
    const float* __restrict__ etype_emb, const float* __restrict__ btype_emb,
    const float* __restrict__ bconj_emb, const float* __restrict__ bring_emb,
    const float* __restrict__ bstereo_emb,
    const float* __restrict__ refW, const float* __restrict__ refb,
    float* __restrict__ agg)
{
    __shared__ unsigned short wl[ETM * WLP];     // 12.9 KB (bf16 w)
    __shared__ unsigned short hsl[ETM * HSP];    // 17.2 KB staged src rows
    __shared__ float svl[ETM * VDIM];            // 2 KB staged sv rows
    __shared__ unsigned short As[ETM * AP1];     // 2.3 KB
    __shared__ int srcl[ETM], dstl[ETM];
    __shared__ int itype[ETM], ibt[ETM], ibc[ETM], ibr[ETM], ibs[ETM];
    __shared__ float distl[ETM], erdl[ETM], y1l[ETM][3];

    const int tid = threadIdx.x;
    const int bid = (blockIdx.x & 7) * 1250 + (blockIdx.x >> 3);   // XCD swizzle
    const int e0 = bid * ETM;

    if (tid < ETM) {
        int ge = perm[e0 + tid];
        int s = eidx[ge], d = eidx[NE + ge];
        srcl[tid] = s; dstl[tid] = d;
        itype[tid] = etype[ge]; ibt[tid] = ebt[ge]; ibc[tid] = ebc[ge];
        ibr[tid] = ebr[ge]; ibs[tid] = ebs[ge];
        float dx = coords[d*3+0] - coords[s*3+0];
        float dy = coords[d*3+1] - coords[s*3+1];
        float dz = coords[d*3+2] - coords[s*3+2];
        float dist = sqrtf(dx*dx + dy*dy + dz*dz);
        distl[tid] = dist;
        float inv = 1.f / (dist + 1e-8f);
        y1l[tid][0] = dx * inv; y1l[tid][1] = dy * inv; y1l[tid][2] = dz * inv;
        erdl[tid] = erd[ge];
    }
    __syncthreads();

    // ---- bulk-stage src rows of hb + sv into LDS (512 threads)
    {
        for (int i = tid; i < ETM * 66; i += 512) {
            int e = i / 66, j = i - e * 66;
            bf16x8 v = *(const bf16x8*)&hb[(size_t)srcl[e] * FEAT + j * 8];
            *(bf16x8*)&hsl[e * HSP + j * 8] = v;
        }
        // ETM*VDIM == 512: one element per thread
        svl[tid] = sv[(size_t)srcl[tid >> 5] * VDIM + (tid & 31)];
    }

    // ---- stage misc features (k<60, padded to 64) as bf16
    {
        const int k = tid & 63;
        const int ebase = tid >> 6;          // 0..7
        #pragma unroll
        for (int it = 0; it < 2; ++it) {
            int e = it * 8 + ebase;
            float de = distl[e];
            float v;
            if (k >= 60) v = 0.f;
            else if (k < 16) { float x = (de - (float)k * (10.f/15.f)) * 1.6f; v = expf(-x*x); }
            else if (k < 32) v = etype_emb[itype[e]*16 + (k-16)];
            else if (k < 40) v = btype_emb[ibt[e]*8 + (k-32)];
            else if (k < 44) v = bconj_emb[ibc[e]*4 + (k-40)];
            else if (k < 48) v = bring_emb[ibr[e]*4 + (k-44)];
            else if (k < 52) v = bstereo_emb[ibs[e]*4 + (k-48)];
            else {
                int j = k - 52;
                float dd = de - erdl[e];
                float hr = erdl[e] > 0.f ? 1.f : 0.f;
                v = fabsf(dd)*refW[j] + dd*refW[8+j] + hr*refW[16+j] + refb[j];
            }
            As[e * AP1 + k] = f2bf(v);
        }
    }
    __syncthreads();

    // ---- tiny MFMA GEMM (misc) + fused srcdst gather-add (8 waves, 4 tiles each)
    const int wid = tid >> 6, lane = tid & 63;
    const int lr = lane & 15, lkb = (lane >> 4) << 3;
    const int nt0 = wid * 3;                  // 25 tiles / 8 waves: tiles nt0..nt0+3 (max 24)
    const int rbase = (lane >> 4) << 2;
    {
        f32x4 acc[4];
        #pragma unroll
        for (int t = 0; t < 4; ++t) acc[t] = (f32x4){0.f, 0.f, 0.f, 0.f};

        #pragma unroll
        for (int ks = 0; ks < 2; ++ks) {
            int kb = ks * 32 + lkb;
            bf16x8 a0 = *(const bf16x8*)&As[lr * AP1 + kb];
            #pragma unroll
            for (int t = 0; t < 4; ++t) {
                bf16x8 b = *(const bf16x8*)&Wt1[(size_t)((nt0 + t) * 16 + lr) * 64 + kb];
                acc[t] = __builtin_amdgcn_mfma_f32_16x16x32_bf16(a0, b, acc[t], 0, 0, 0);
            }
        }
        int se[4], de_[4];
        #pragma unroll
        for (int r = 0; r < 4; ++r) { se[r] = srcl[rbase + r]; de_[r] = dstl[rbase + r]; }
        #pragma unroll
        for (int t = 0; t < 4; ++t) {
            const int col = (nt0 + t) * 16 + lr;
            #pragma unroll
            for (int r = 0; r < 4; ++r) {
                float add = bf2f(srcdst[(size_t)se[r] * 800 + col])
                          + bf2f(srcdst[(size_t)de_[r] * 800 + 400 + col]);
                wl[(rbase + r) * WLP + col] = f2bf(acc[t][r] + add);
            }
        }
    }
    __syncthreads();

    // ---- messages with run-accumulation; 512 threads: tid<256 -> A (+C for tid<16), tid>=256 -> B
    {
        const bool isA = tid < 256;
        const bool hasC = tid < 16;
        const int jC = 64 + tid;
        const int hoffC = 448 + jC;           // 512..527 (tid<16)
        const int wC = 384 + jC / 5;

        int cls = 0, cc = 0, ii = 0, ia = 0, ib = 0, hoff = 0, wB1 = 0, wB2 = 0;
        if (!isA) {
            int j = tid - 256;                // 0..255
            if (j < 96)       { cls = 0; cc = j / 3;                 ii = j % 3;  hoff = 256 + j;  wB1 = 256 + cc; wB2 = 288 + cc; }
            else if (j < 192) { int j2 = j - 96; cls = 1; cc = j2 / 3; ii = j2 % 3; hoff = 352 + j2; wB1 = 320 + cc; wB2 = 352 + cc; }
            else              { int j2 = j - 192; cls = 2; cc = j2 / 5;             hoff = 448 + j2; wB1 = 384 + cc; }
            ia = (ii + 1) % 3; ib = (ii + 2) % 3;
        }

        float accA = 0.f, accB = 0.f, accC = 0.f;
        for (int e = 0; e < ETM; ++e) {
            const unsigned short* hs = &hsl[e * HSP];
            if (isA) {
                accA = fmaf(bf2f(wl[e * WLP + tid]), bf2f(hs[tid]), accA);
                if (hasC) accC = fmaf(bf2f(wl[e * WLP + wC]), bf2f(hs[hoffC]), accC);
            } else {
                float m;
                if (cls == 0) {
                    float wv1 = bf2f(wl[e * WLP + wB1]), wsv = bf2f(wl[e * WLP + wB2]);
                    m = wv1 * bf2f(hs[hoff]) + wsv * svl[e * VDIM + cc] * y1l[e][ii];
                } else if (cls == 1) {
                    float wv2 = bf2f(wl[e * WLP + wB1]), wcx = bf2f(wl[e * WLP + wB2]);
                    float va = bf2f(hs[256 + cc * 3 + ia]), vb = bf2f(hs[256 + cc * 3 + ib]);
                    m = wv2 * bf2f(hs[hoff]) + wcx * (va * y1l[e][ib] - vb * y1l[e][ia]);
                } else {
                    m = bf2f(wl[e * WLP + wB1]) * bf2f(hs[hoff]);
                }
                accB += m;
            }

            bool fl = (e == ETM - 1) || (dstl[e + 1] != dstl[e]);
            if (fl) {
                int d = dstl[e];
                if (isA) {
                    atomicAdd(&agg[(size_t)d * FEAT + tid], accA);
                    if (hasC) atomicAdd(&agg[(size_t)d * FEAT + hoffC], accC);
                } else {
                    atomicAdd(&agg[(size_t)d * FEAT + 256 + (tid - 256)], accB);
                }
                accA = 0.f; accB = 0.f; accC = 0.f;
            }
        }
    }
}

// ================================================================ proj kernel: us = silu(agg_s*DEG_INV @ proj_s) (bf16 out)
__global__ __launch_bounds__(256) void proj_kernel(
    const float* __restrict__ agg, const unsigned short* __restrict__ Ps,
    unsigned short* __restrict__ us_buf)
{
    __shared__ unsigned short As3[32 * AP3];
    const int tid = threadIdx.x;
    const int n0 = blockIdx.x * 32;

    for (int e = 0; e < 32; ++e) {
        int n = n0 + e;
        float v = (n < NN) ? agg[(size_t)n * FEAT + tid] * DEG_INV : 0.f;
        As3[e * AP3 + tid] = f2bf(v);
    }
    __syncthreads();

    const int wid = tid >> 6, lane = tid & 63;
    const int lr = lane & 15, lkb = (lane >> 4) << 3;
    const int rbase = (lane >> 4) << 2;
    const int nt0 = wid * 4;          // 16 tiles over 4 waves

    f32x4 acc[2][4];
    #pragma unroll
    for (int m = 0; m < 2; ++m)
        #pragma unroll
        for (int t = 0; t < 4; ++t) acc[m][t] = (f32x4){0.f, 0.f, 0.f, 0.f};

    for (int ks = 0; ks < 8; ++ks) {
        int kb = ks * 32 + lkb;
        bf16x8 a0 = *(const bf16x8*)&As3[lr * AP3 + kb];
        bf16x8 a1 = *(const bf16x8*)&As3[(16 + lr) * AP3 + kb];
        #pragma unroll
        for (int t = 0; t < 4; ++t) {
            bf16x8 b = *(const bf16x8*)&Ps[(size_t)((nt0 + t) * 16 + lr) * 256 + kb];
            acc[0][t] = __builtin_amdgcn_mfma_f32_16x16x32_bf16(a0, b, acc[0][t], 0, 0, 0);
            acc[1][t] = __builtin_amdgcn_mfma_f32_16x16x32_bf16(a1, b, acc[1][t], 0, 0, 0);
        }
    }
    #pragma unroll
    for (int t = 0; t < 4; ++t) {
        int col = (nt0 + t) * 16 + lr;
        #pragma unroll
        for (int m = 0; m < 2; ++m) {
            #pragma unroll
            for (int r = 0; r < 4; ++r) {
                int n = n0 + m * 16 + rbase + r;
                if (n < NN) {
                    float x = acc[m][t][r];
                    us_buf[(size_t)n * SDIM + col] = f2bf(x / (1.f + expf(-x)));
                }
            }
        }
    }
}

// ================================================================ node kernel: wave-per-node, 4 nodes/block
__global__ __launch_bounds__(256) void node_kernel(
    const float* __restrict__ hcur, const float* __restrict__ ada_buf,
    const float* __restrict__ agg, const unsigned short* __restrict__ us_buf,
    const float* __restrict__ pv1, const float* __restrict__ pv2,
    const float* __restrict__ pl2,
    float* __restrict__ hnext, unsigned short* __restrict__ hbnext)
{
    __shared__ float plv1[VDIM * VDIM];
    __shared__ float plv2[VDIM * VDIM];
    __shared__ float pll2[L2DIM * L2DIM];
    __shared__ float avl[4][272];

    const int tid = threadIdx.x;
    for (int i = tid; i < VDIM * VDIM; i += 256) { plv1[i] = pv1[i]; plv2[i] = pv2[i]; }
    if (tid < L2DIM * L2DIM) pll2[tid] = pl2[tid];

    const int w = tid >> 6, lane = tid & 63;
    const int n = blockIdx.x * 4 + w;
    const size_t nb = (size_t)n * FEAT;
    const size_t na = (size_t)n * ADA;

    for (int i = lane; i < 272; i += 64) avl[w][i] = agg[nb + 256 + i] * DEG_INV;
    __syncthreads();

    // ---- s: LayerNorm with ada scale/shift
    float snv[4];
    float ssum = 0.f, ssq = 0.f;
    #pragma unroll
    for (int j = 0; j < 4; ++j) {
        int c = lane + 64 * j;
        float v = hcur[nb + c] + bf2f(us_buf[(size_t)n * SDIM + c]);
        snv[j] = v; ssum += v; ssq += v * v;
    }
    #pragma unroll
    for (int off = 32; off > 0; off >>= 1) {
        ssum += __shfl_xor(ssum, off, 64);
        ssq  += __shfl_xor(ssq, off, 64);
    }
    float mu = ssum * (1.f / SDIM);
    float var = ssq * (1.f / SDIM) - mu * mu;
    float rstd = rsqrtf(var + 1e-5f);
    #pragma unroll
    for (int j = 0; j < 4; ++j) {
        int c = lane + 64 * j;
        float o = (snv[j] - mu) * rstd * (1.f + ada_buf[na + c]) + ada_buf[na + SDIM + c];
        hnext[nb + c] = o;
        if (hbnext) hbnext[nb + c] = f2bf(o);
    }

    // ---- v1o / v1e / l2 projections + residual + vnorms
    float vb[5];
    float S1 = 0.f, S2 = 0.f, S3 = 0.f;
    #pragma unroll
    for (int j = 0; j < 5; ++j) {
        int c = (j < 4) ? (lane + 64 * j) : (256 + lane);
        bool ok = (j < 4) || (lane < 16);
        float val = 0.f;
        if (ok) {
            if (c < 96) {
                int d = c / 3, i = c - 3 * d;
                float a = 0.f;
                #pragma unroll
                for (int k = 0; k < VDIM; ++k) a = fmaf(avl[w][k*3 + i], plv1[k * VDIM + d], a);
                val = hcur[nb + SDIM + c] + a;
                S1 += val * val;
            } else if (c < 192) {
                int c2 = c - 96;
                int d = c2 / 3, i = c2 - 3 * d;
                float a = 0.f;
                #pragma unroll
                for (int k = 0; k < VDIM; ++k) a = fmaf(avl[w][96 + k*3 + i], plv2[k * VDIM + d], a);
                val = hcur[nb + SDIM + c] + a;
                S2 += val * val;
            } else {
                int c2 = c - 192;
                int d = c2 / 5, i = c2 - 5 * d;
                float a = 0.f;
                #pragma unroll
                for (int k = 0; k < L2DIM; ++k) a = fmaf(avl[w][192 + k*5 + i], pll2[k * L2DIM + d], a);
                val = hcur[nb + SDIM + c] + a;
                S3 += val * val;
            }
        }
        vb[j] = val;
    }
    #pragma unroll
    for (int off = 32; off > 0; off >>= 1) {
        S1 += __shfl_xor(S1, off, 64);
        S2 += __shfl_xor(S2, off, 64);
        S3 += __shfl_xor(S3, off, 64);
    }
    float r1 = rsqrtf(S1 * (1.f / VDIM) + 1e-5f);
    float r2 = rsqrtf(S2 * (1.f / VDIM) + 1e-5f);
    float r3 = rsqrtf(S3 * (1.f / L2DIM) + 1e-5f);

    #pragma unroll
    for (int j = 0; j < 5; ++j) {
        int c = (j < 4) ? (lane + 64 * j) : (256 + lane);
        bool ok = (j < 4) || (lane < 16);
        if (ok) {
            float o;
            if (c < 96) {
                int d = c / 3;
                o = vb[j] * r1 * (1.f + ada_buf[na + 2*SDIM + d]);
            } else if (c < 192) {
                int d = (c - 96) / 3;
                o = vb[j] * r2 * (1.f + ada_buf[na + 2*SDIM + VDIM + d]);
            } else {
                int d = (c - 192) / 5;
                o = vb[j] * r3 * (1.f + ada_buf[na + 2*SDIM + 2*VDIM + d]);
            }
            hnext[nb + SDIM + c] = o;
            if (hbnext) hbnext[nb + SDIM + c] = f2bf(o);
        }
    }
}

// ================================================================ launch
extern "C" void kernel_launch(void* const* d_in, const int* in_sizes, int n_in,
                              void* d_out, int out_size, void* d_ws, size_t ws_size,
                              hipStream_t stream) {
    const float* h_in   = (const float*)d_in[0];
    const float* coords = (const float*)d_in[1];
    const float* erd    = (const float*)d_in[2];
    const float* t_emb  = (const float*)d_in[3];
    const float* etype_emb   = (const float*)d_in[4];
    const float* btype_emb   = (const float*)d_in[5];
    const float* bconj_emb   = (const float*)d_in[6];
    const float* bring_emb   = (const float*)d_in[7];
    const float* bstereo_emb = (const float*)d_in[8];
    const float* refW   = (const float*)d_in[9];
    const float* refb   = (const float*)d_in[10];
    const float* edgeW  = (const float*)d_in[11];
    const float* edgeb  = (const float*)d_in[12];
    const float* svW    = (const float*)d_in[13];
    const float* proj_s = (const float*)d_in[14];
    const float* proj_v1= (const float*)d_in[15];
    const float* proj_v2= (const float*)d_in[16];
    const float* proj_l2= (const float*)d_in[17];
    const float* adaW   = (const float*)d_in[18];
    const float* adab   = (const float*)d_in[19];
    const int* eidx     = (const int*)d_in[20];
    const int* etype    = (const int*)d_in[21];
    const int* ebt      = (const int*)d_in[22];
    const int* ebc      = (const int*)d_in[23];
    const int* ebr      = (const int*)d_in[24];
    const int* ebs      = (const int*)d_in[25];

    float* ws_f     = (float*)d_ws;
    float* sv       = ws_f;                           // N*32
    float* agg      = sv + (size_t)NN * VDIM;         // N*528
    float* h1       = agg + (size_t)NN * FEAT;        // N*528
    float* ada_buf  = h1 + (size_t)NN * FEAT;         // N*592
    float* us_f     = ada_buf + (size_t)NN * ADA;     // N*256 slot (used as bf16)
    unsigned short* us_buf = (unsigned short*)us_f;
    unsigned short* srcdst = (unsigned short*)(us_f + (size_t)NN * SDIM);    // N*800
    unsigned short* hb     = srcdst + (size_t)NN * 800;                      // N*528
    unsigned short* Wt1    = hb + (size_t)NN * FEAT;                         // 400*64
    unsigned short* Bn     = Wt1 + (size_t)WOUT * 64;                        // 800*384
    unsigned short* Ba     = Bn + (size_t)800 * 384;                         // 592*128
    unsigned short* Bsv    = Ba + (size_t)ADA * 128;                         // 32*256
    unsigned short* Ps     = Bsv + (size_t)VDIM * 256;                       // 256*256
    int* cnt    = (int*)(Ps + (size_t)SDIM * 256);    // N
    int* cursor = cnt + NN;                           // N
    int* perm   = cursor + NN;                        // E

    // ---- sort edges by dst (once; reused by both layers)
    hipMemsetAsync(cnt, 0, NN * sizeof(int), stream);
    hist_kernel<<<(NE + 255) / 256, 256, 0, stream>>>(eidx, cnt);
    scan_kernel<<<1, 1024, 0, stream>>>(cnt, cursor);
    scatter_kernel<<<(NE + 255) / 256, 256, 0, stream>>>(eidx, cursor, perm);
    hb_kernel<<<(NN * FEAT / 4 + 255) / 256, 256, 0, stream>>>(h_in, hb);

    for (int l = 0; l < 2; ++l) {
        const float* hcur = (l == 0) ? h_in : h1;
        float* hnext      = (l == 0) ? h1 : (float*)d_out;
        const float* W    = edgeW + (size_t)l * 700 * WOUT;

        hipMemsetAsync(agg, 0, (size_t)NN * FEAT * sizeof(float), stream);
        prep_kernel<<<(O5 + 255) / 256, 256, 0, stream>>>(
            W, adaW + (size_t)l * TDIM * ADA, svW + (size_t)l * SDIM * VDIM,
            proj_s + (size_t)l * SDIM * SDIM, Wt1, Bn, Ba, Bsv, Ps);
        nodeproj_kernel<<<(NN + 31) / 32, 256, 0, stream>>>(
            hb, t_emb, Bn, Ba, Bsv, edgeb + l * WOUT, adab + l * ADA,
            srcdst, ada_buf, sv);
        edge_kernel<<<NE / ETM, 512, 0, stream>>>(
            hb, coords, erd, sv, Wt1, srcdst, perm,
            eidx, etype, ebt, ebc, ebr, ebs,
            etype_emb + l * 144, btype_emb + l * 48, bconj_emb + l * 12,
            bring_emb + l * 12, bstereo_emb + l * 20,
            refW + l * 24, refb + l * 8,
            agg);
        proj_kernel<<<(NN + 31) / 32, 256, 0, stream>>>(agg, Ps, us_buf);
        node_kernel<<<NN / 4, 256, 0, stream>>>(
            hcur, ada_buf, agg, us_buf,
            proj_v1 + l * VDIM * VDIM, proj_v2 + l * VDIM * VDIM,
            proj_l2 + l * L2DIM * L2DIM,
            hnext, (l == 0) ? hb : (unsigned short*)nullptr);
    }
}